// Round 6
// baseline (833.980 us; speedup 1.0000x reference)
//
#include <hip/hip_runtime.h>
#include <hip/hip_bf16.h>

#define NN 10000
#define INC 32
#define OUTC 32
#define EF 16
#define NE 320000

typedef __attribute__((ext_vector_type(8)))  __bf16 bf16x8;
typedef __attribute__((ext_vector_type(16))) float  f32x16;
typedef __attribute__((ext_vector_type(4)))  float  f32x4;

// ======================= zero cnt =======================
__global__ void zero_kernel(int* __restrict__ cnt) {
    int gid = blockIdx.x * 256 + threadIdx.x;
    if (gid < NN) cnt[gid] = 0;
}

// ======================= CSR build =======================
__global__ void hist_kernel(const int* __restrict__ eidx, int* __restrict__ cnt) {
    for (int e = blockIdx.x * 256 + threadIdx.x; e < NE; e += gridDim.x * 256)
        atomicAdd(&cnt[eidx[NE + e]], 1);
}

// single block, 1024 threads: exclusive scan of cnt[0..NN) -> offs, copy to pos
__global__ __launch_bounds__(1024) void scan_kernel(const int* __restrict__ cnt,
                                                    int* __restrict__ offs,
                                                    int* __restrict__ pos) {
    __shared__ int s[1024];
    const int t = threadIdx.x;
    const int base = t * 10;
    int loc[10];
    int sum = 0;
    #pragma unroll
    for (int k = 0; k < 10; ++k) {
        int idx = base + k;
        int v = (idx < NN) ? cnt[idx] : 0;
        loc[k] = sum;
        sum += v;
    }
    s[t] = sum;
    __syncthreads();
    for (int off = 1; off < 1024; off <<= 1) {
        int v = 0;
        if (t >= off) v = s[t - off];
        __syncthreads();
        if (t >= off) s[t] += v;
        __syncthreads();
    }
    int excl = (t > 0) ? s[t - 1] : 0;
    #pragma unroll
    for (int k = 0; k < 10; ++k) {
        int idx = base + k;
        if (idx < NN) {
            int o = excl + loc[k];
            offs[idx] = o;
            pos[idx]  = o;
        }
    }
    if (t == 1023) offs[NN] = s[1023];
}

// also emits srcs[] so the edge kernel reads src sequentially (no eidx gather)
__global__ void scatter_kernel(const int* __restrict__ eidx, int* __restrict__ pos,
                               int* __restrict__ perm, int* __restrict__ srcs) {
    for (int e = blockIdx.x * 256 + threadIdx.x; e < NE; e += gridDim.x * 256) {
        int d = eidx[NE + e];
        int s = eidx[e];
        int p = atomicAdd(&pos[d], 1);
        perm[p] = e;
        srcs[p] = s;
    }
}

// ======================= node-centric fused edge kernel =======================
// One wave per dst node n. Walk CSR segment in 32-edge chunks via MFMA
// 32x32x16 bf16 (A = W_edge cols from LDS, B = edge_attr rows, C = bias).
// msgr accumulates in registers across chunks; one xor-butterfly at the end;
// two lanes store 4 x float4. No atomics. __launch_bounds__(256,3) is
// REQUIRED: without it the allocator balloons to 256 VGPR and spills ~44KB
// per chunk (round-5: 677 MB scratch writes, 353 us).
__global__ __launch_bounds__(256, 3) void edge_node_kernel(
    const float* __restrict__ x, const float* __restrict__ ea,
    const float* __restrict__ W, const float* __restrict__ be,
    const int* __restrict__ offs, const int* __restrict__ perm,
    const int* __restrict__ srcs, float* __restrict__ out)
{
    __shared__ __attribute__((aligned(16))) __bf16 WT[32][2][32][8];  // 32 KiB
    __shared__ __attribute__((aligned(16))) float  BPF[32][2][16];    // 4 KiB

    const int tid = threadIdx.x;

    #pragma unroll
    for (int k = 0; k < 8; ++k) {
        int idx = tid + k * 256;              // (cb, hi, c)
        int cb = idx >> 6, rem = idx & 63, hi2 = rem >> 5, c = rem & 31;
        int cg = cb * 32 + c;
        #pragma unroll
        for (int j = 0; j < 8; ++j)
            WT[cb][hi2][c][j] = (__bf16)W[(8 * hi2 + j) * 1024 + cg];
    }
    #pragma unroll
    for (int k = 0; k < 4; ++k) {
        int idx = tid + k * 256;              // (cb, hi, r)
        int cb = idx >> 5, rem = idx & 31, hi2 = rem >> 4, r = rem & 15;
        int row = (r & 3) + 8 * (r >> 2) + 4 * hi2;
        BPF[cb][hi2][r] = be[cb * 32 + row];
    }
    __syncthreads();

    const int lane = tid & 63;
    const int hi   = lane >> 5;
    const int l31  = lane & 31;
    const int n    = blockIdx.x * 4 + (tid >> 6);   // exact: gridDim.x = NN/4

    const int a   = offs[n];
    const int b   = offs[n + 1];
    const int deg = b - a;

    float msgr[16];
    #pragma unroll
    for (int r = 0; r < 16; ++r) msgr[r] = 0.0f;

    for (int c0 = 0; c0 < deg; c0 += 32) {
        const int idx  = c0 + l31;
        const bool act = idx < deg;
        const int j    = a + (act ? idx : deg - 1);   // clamp inside segment
        const int e    = __builtin_nontemporal_load(perm + j);
        const int src  = __builtin_nontemporal_load(srcs + j);

        const f32x4* eap = (const f32x4*)(ea + e * 16 + hi * 8);
        f32x4 f0 = __builtin_nontemporal_load(eap);
        f32x4 f1 = __builtin_nontemporal_load(eap + 1);
        bf16x8 bfrag;
        bfrag[0] = (__bf16)f0.x; bfrag[1] = (__bf16)f0.y;
        bfrag[2] = (__bf16)f0.z; bfrag[3] = (__bf16)f0.w;
        bfrag[4] = (__bf16)f1.x; bfrag[5] = (__bf16)f1.y;
        bfrag[6] = (__bf16)f1.z; bfrag[7] = (__bf16)f1.w;

        const float4* xp = (const float4*)(x + src * 32);

        #pragma unroll
        for (int cbq = 0; cbq < 8; ++cbq) {
            float4 xq = xp[cbq];
            if (!act) { xq.x = 0.0f; xq.y = 0.0f; xq.z = 0.0f; xq.w = 0.0f; }
            #pragma unroll
            for (int c4 = 0; c4 < 4; ++c4) {
                const int cb = cbq * 4 + c4;
                bf16x8 af = *(const bf16x8*)(&WT[cb][hi][l31][0]);
                const f32x16* bp = (const f32x16*)(&BPF[cb][hi][0]);
                f32x16 acc = __builtin_amdgcn_mfma_f32_32x32x16_bf16(af, bfrag, *bp, 0, 0, 0);
                const float xv = (c4 == 0) ? xq.x : (c4 == 1) ? xq.y : (c4 == 2) ? xq.z : xq.w;
                #pragma unroll
                for (int r = 0; r < 16; ++r)
                    msgr[r] += fmaxf(acc[r], 0.0f) * xv;
            }
        }
    }

    // reduce across the 32 slot-lanes within each hi-half (masks < 32 never cross)
    #pragma unroll
    for (int m = 1; m <= 16; m <<= 1) {
        #pragma unroll
        for (int r = 0; r < 16; ++r)
            msgr[r] += __shfl_xor(msgr[r], m, 64);
    }

    const float rdeg = (deg > 0) ? (1.0f / (float)deg) : 0.0f;
    if (l31 == 0) {
        float4* orow = (float4*)(out + (size_t)n * 32);
        #pragma unroll
        for (int q = 0; q < 4; ++q)
            orow[2 * q + hi] = make_float4(msgr[4*q] * rdeg, msgr[4*q+1] * rdeg,
                                           msgr[4*q+2] * rdeg, msgr[4*q+3] * rdeg);
    }
}

// ======================= finalize: out += x@root + bias =======================
__global__ __launch_bounds__(256) void finalize_kernel(
    const float* __restrict__ x, const float* __restrict__ root,
    const float* __restrict__ bias, float* __restrict__ out)
{
    int gid = blockIdx.x * 256 + threadIdx.x;
    if (gid >= NN * 32) return;
    int n = gid >> 5, o = gid & 31;
    float acc = out[gid] + bias[o];
    const float* xr = x + n * 32;
    #pragma unroll
    for (int i = 0; i < 32; ++i)
        acc += xr[i] * root[i * 32 + o];
    out[gid] = acc;
}

// ======================= launch =======================
extern "C" void kernel_launch(void* const* d_in, const int* in_sizes, int n_in,
                              void* d_out, int out_size, void* d_ws, size_t ws_size,
                              hipStream_t stream) {
    const float* x    = (const float*)d_in[0];
    const int*   eidx = (const int*)d_in[1];     // [2][NE]
    const float* ea   = (const float*)d_in[2];   // [NE][16]
    const float* W    = (const float*)d_in[3];   // [16][1024]
    const float* be   = (const float*)d_in[4];   // [1024]
    const float* root = (const float*)d_in[5];   // [32][32]
    const float* bias = (const float*)d_in[6];   // [32]
    float* out = (float*)d_out;

    // ws (ints): cnt[NN] | offs[NN+1] | pos[NN] | perm[NE] | srcs[NE]
    int* cnt  = (int*)d_ws;
    int* offs = cnt + NN;
    int* pos  = offs + NN + 1;
    int* perm = pos + NN;
    int* srcs = perm + NE;

    zero_kernel<<<(NN + 255) / 256, 256, 0, stream>>>(cnt);
    hist_kernel<<<640, 256, 0, stream>>>(eidx, cnt);
    scan_kernel<<<1, 1024, 0, stream>>>(cnt, offs, pos);
    scatter_kernel<<<640, 256, 0, stream>>>(eidx, pos, perm, srcs);
    edge_node_kernel<<<NN / 4, 256, 0, stream>>>(x, ea, W, be, offs, perm, srcs, out);
    finalize_kernel<<<(NN * 32 + 255) / 256, 256, 0, stream>>>(x, root, bias, out);
}

// Round 7
// 138.500 us; speedup vs baseline: 6.0215x; 6.0215x over previous
//
#include <hip/hip_runtime.h>
#include <hip/hip_bf16.h>

#define NN 10000
#define INC 32
#define OUTC 32
#define EF 16
#define NE 320000

typedef __attribute__((ext_vector_type(8)))  __bf16 bf16x8;
typedef __attribute__((ext_vector_type(16))) float  f32x16;
typedef __attribute__((ext_vector_type(4)))  float  f32x4;

// ======================= zero cnt =======================
__global__ void zero_kernel(int* __restrict__ cnt) {
    int gid = blockIdx.x * 256 + threadIdx.x;
    if (gid < NN) cnt[gid] = 0;
}

// ======================= CSR build =======================
__global__ void hist_kernel(const int* __restrict__ eidx, int* __restrict__ cnt) {
    for (int e = blockIdx.x * 256 + threadIdx.x; e < NE; e += gridDim.x * 256)
        atomicAdd(&cnt[eidx[NE + e]], 1);
}

// single block, 1024 threads: exclusive scan of cnt[0..NN) -> offs, copy to pos
__global__ __launch_bounds__(1024) void scan_kernel(const int* __restrict__ cnt,
                                                    int* __restrict__ offs,
                                                    int* __restrict__ pos) {
    __shared__ int s[1024];
    const int t = threadIdx.x;
    const int base = t * 10;
    int loc[10];
    int sum = 0;
    #pragma unroll
    for (int k = 0; k < 10; ++k) {
        int idx = base + k;
        int v = (idx < NN) ? cnt[idx] : 0;
        loc[k] = sum;
        sum += v;
    }
    s[t] = sum;
    __syncthreads();
    for (int off = 1; off < 1024; off <<= 1) {
        int v = 0;
        if (t >= off) v = s[t - off];
        __syncthreads();
        if (t >= off) s[t] += v;
        __syncthreads();
    }
    int excl = (t > 0) ? s[t - 1] : 0;
    #pragma unroll
    for (int k = 0; k < 10; ++k) {
        int idx = base + k;
        if (idx < NN) {
            int o = excl + loc[k];
            offs[idx] = o;
            pos[idx]  = o;
        }
    }
    if (t == 1023) offs[NN] = s[1023];
}

// also emits srcs[] so the edge kernel reads src sequentially (no eidx gather)
__global__ void scatter_kernel(const int* __restrict__ eidx, int* __restrict__ pos,
                               int* __restrict__ perm, int* __restrict__ srcs) {
    for (int e = blockIdx.x * 256 + threadIdx.x; e < NE; e += gridDim.x * 256) {
        int d = eidx[NE + e];
        int s = eidx[e];
        int p = atomicAdd(&pos[d], 1);
        perm[p] = e;
        srcs[p] = s;
    }
}

// ======================= node-centric fused edge kernel =======================
// One wave per dst node n. Walk CSR segment in 32-edge chunks via MFMA
// 32x32x16 bf16 (A = W_edge cols from LDS, B = edge_attr rows, C = bias).
// msgr accumulates in registers across chunks; one xor-butterfly; two lanes
// store 4 x float4. No atomics.
//
// SPILL TRAP (rounds 5/6): the per-cb LDS reads (A-frag 32x4 regs, bias C
// 32x16 regs) are chunk-loop-invariant; LICM hoists ~640 regs -> scratch
// spill INSIDE the loop (measured 0.7-2.7 GB scratch traffic). Fixes:
//  - opaque cbo (asm "+v") so the LDS addresses can't be proven invariant
//  - sched_barrier(0) per cb so only ~1 acc tile is live at a time
__global__ __launch_bounds__(256, 3) void edge_node_kernel(
    const float* __restrict__ x, const float* __restrict__ ea,
    const float* __restrict__ W, const float* __restrict__ be,
    const int* __restrict__ offs, const int* __restrict__ perm,
    const int* __restrict__ srcs, float* __restrict__ out)
{
    __shared__ __attribute__((aligned(16))) __bf16 WT[32][2][32][8];  // 32 KiB
    __shared__ __attribute__((aligned(16))) float  BPF[32][2][16];    // 4 KiB

    const int tid = threadIdx.x;

    #pragma unroll
    for (int k = 0; k < 8; ++k) {
        int idx = tid + k * 256;              // (cb, hi, c)
        int cb = idx >> 6, rem = idx & 63, hi2 = rem >> 5, c = rem & 31;
        int cg = cb * 32 + c;
        #pragma unroll
        for (int j = 0; j < 8; ++j)
            WT[cb][hi2][c][j] = (__bf16)W[(8 * hi2 + j) * 1024 + cg];
    }
    #pragma unroll
    for (int k = 0; k < 4; ++k) {
        int idx = tid + k * 256;              // (cb, hi, r)
        int cb = idx >> 5, rem = idx & 31, hi2 = rem >> 4, r = rem & 15;
        int row = (r & 3) + 8 * (r >> 2) + 4 * hi2;
        BPF[cb][hi2][r] = be[cb * 32 + row];
    }
    __syncthreads();

    const int lane = tid & 63;
    const int hi   = lane >> 5;
    const int l31  = lane & 31;
    const int n    = blockIdx.x * 4 + (tid >> 6);   // exact: gridDim.x = NN/4

    const int a   = offs[n];
    const int b   = offs[n + 1];
    const int deg = b - a;

    float msgr[16];
    #pragma unroll
    for (int r = 0; r < 16; ++r) msgr[r] = 0.0f;

    for (int c0 = 0; c0 < deg; c0 += 32) {
        const int idx  = c0 + l31;
        const bool act = idx < deg;
        const int j    = a + (act ? idx : deg - 1);   // clamp inside segment
        const int e    = __builtin_nontemporal_load(perm + j);
        const int src  = __builtin_nontemporal_load(srcs + j);

        const f32x4* eap = (const f32x4*)(ea + e * 16 + hi * 8);
        f32x4 f0 = __builtin_nontemporal_load(eap);
        f32x4 f1 = __builtin_nontemporal_load(eap + 1);
        bf16x8 bfrag;
        bfrag[0] = (__bf16)f0.x; bfrag[1] = (__bf16)f0.y;
        bfrag[2] = (__bf16)f0.z; bfrag[3] = (__bf16)f0.w;
        bfrag[4] = (__bf16)f1.x; bfrag[5] = (__bf16)f1.y;
        bfrag[6] = (__bf16)f1.z; bfrag[7] = (__bf16)f1.w;

        const float4* xp = (const float4*)(x + src * 32);

        #pragma unroll
        for (int cbq = 0; cbq < 8; ++cbq) {
            float4 xq = xp[cbq];
            if (!act) { xq.x = 0.0f; xq.y = 0.0f; xq.z = 0.0f; xq.w = 0.0f; }
            #pragma unroll
            for (int c4 = 0; c4 < 4; ++c4) {
                int cbo = cbq * 4 + c4;
                asm volatile("" : "+v"(cbo));   // opaque: defeat LICM/CSE of LDS reads
                bf16x8 af = *(const bf16x8*)(&WT[cbo][hi][l31][0]);
                f32x16 ci = *(const f32x16*)(&BPF[cbo][hi][0]);
                f32x16 acc = __builtin_amdgcn_mfma_f32_32x32x16_bf16(af, bfrag, ci, 0, 0, 0);
                const float xv = (c4 == 0) ? xq.x : (c4 == 1) ? xq.y : (c4 == 2) ? xq.z : xq.w;
                #pragma unroll
                for (int r = 0; r < 16; ++r)
                    msgr[r] += fmaxf(acc[r], 0.0f) * xv;
                __builtin_amdgcn_sched_barrier(0);  // cap acc liveness to ~1 tile
            }
        }
    }

    // reduce across the 32 slot-lanes within each hi-half (masks < 32 never cross)
    #pragma unroll
    for (int m = 1; m <= 16; m <<= 1) {
        #pragma unroll
        for (int r = 0; r < 16; ++r)
            msgr[r] += __shfl_xor(msgr[r], m, 64);
    }

    const float rdeg = (deg > 0) ? (1.0f / (float)deg) : 0.0f;
    if (l31 == 0) {
        float4* orow = (float4*)(out + (size_t)n * 32);
        #pragma unroll
        for (int q = 0; q < 4; ++q)
            orow[2 * q + hi] = make_float4(msgr[4*q] * rdeg, msgr[4*q+1] * rdeg,
                                           msgr[4*q+2] * rdeg, msgr[4*q+3] * rdeg);
    }
}

// ======================= finalize: out += x@root + bias =======================
__global__ __launch_bounds__(256) void finalize_kernel(
    const float* __restrict__ x, const float* __restrict__ root,
    const float* __restrict__ bias, float* __restrict__ out)
{
    int gid = blockIdx.x * 256 + threadIdx.x;
    if (gid >= NN * 32) return;
    int n = gid >> 5, o = gid & 31;
    float acc = out[gid] + bias[o];
    const float* xr = x + n * 32;
    #pragma unroll
    for (int i = 0; i < 32; ++i)
        acc += xr[i] * root[i * 32 + o];
    out[gid] = acc;
}

// ======================= launch =======================
extern "C" void kernel_launch(void* const* d_in, const int* in_sizes, int n_in,
                              void* d_out, int out_size, void* d_ws, size_t ws_size,
                              hipStream_t stream) {
    const float* x    = (const float*)d_in[0];
    const int*   eidx = (const int*)d_in[1];     // [2][NE]
    const float* ea   = (const float*)d_in[2];   // [NE][16]
    const float* W    = (const float*)d_in[3];   // [16][1024]
    const float* be   = (const float*)d_in[4];   // [1024]
    const float* root = (const float*)d_in[5];   // [32][32]
    const float* bias = (const float*)d_in[6];   // [32]
    float* out = (float*)d_out;

    // ws (ints): cnt[NN] | offs[NN+1] | pos[NN] | perm[NE] | srcs[NE]
    int* cnt  = (int*)d_ws;
    int* offs = cnt + NN;
    int* pos  = offs + NN + 1;
    int* perm = pos + NN;
    int* srcs = perm + NE;

    zero_kernel<<<(NN + 255) / 256, 256, 0, stream>>>(cnt);
    hist_kernel<<<640, 256, 0, stream>>>(eidx, cnt);
    scan_kernel<<<1, 1024, 0, stream>>>(cnt, offs, pos);
    scatter_kernel<<<640, 256, 0, stream>>>(eidx, pos, perm, srcs);
    edge_node_kernel<<<NN / 4, 256, 0, stream>>>(x, ea, W, be, offs, perm, srcs, out);
    finalize_kernel<<<(NN * 32 + 255) / 256, 256, 0, stream>>>(x, root, bias, out);
}